// Round 13
// baseline (219.241 us; speedup 1.0000x reference)
//
#include <hip/hip_runtime.h>
#include <math.h>

// Problem constants (from reference setup_inputs): B=2, S=1024, D=128
#define BB 2
#define SS 1024
#define DD 128

typedef _Float16 v2h __attribute__((ext_vector_type(2)));
typedef _Float16 h16;

__device__ __forceinline__ float fdot2f(v2h a, float c) {
#if __has_builtin(__builtin_amdgcn_fdot2)
    const v2h one = {(h16)1.0f, (h16)1.0f};
    return __builtin_amdgcn_fdot2(a, one, c, false);
#else
    return c + (float)a.x + (float)a.y;
#endif
}

// ---------------------------------------------------------------------------
// Kernel T: transpose the three 128x128 W matrices -> Wt[p][d][f].
// ---------------------------------------------------------------------------
__global__ __launch_bounds__(256) void wt_kernel(
    const float* __restrict__ Wq, const float* __restrict__ Wk,
    const float* __restrict__ Wv, float* __restrict__ Wt)
{
    __shared__ float lt[32 * 129];
    const int p = blockIdx.x >> 2;
    const int f0 = (blockIdx.x & 3) * 32;
    const float* W = (p == 0) ? Wq : (p == 1) ? Wk : Wv;
    const int t = threadIdx.x;

    #pragma unroll
    for (int i = 0; i < 16; ++i) {          // load stripe [32f][128d]
        const int n = i * 256 + t;
        const int fi = n >> 7, d = n & 127;
        lt[fi * 129 + d] = W[(f0 + fi) * 128 + d];
    }
    __syncthreads();
    #pragma unroll
    for (int i = 0; i < 16; ++i) {          // store [128d][32f]
        const int m = i * 256 + t;
        const int d = m >> 5, fo = m & 31;
        Wt[p * 16384 + d * 128 + f0 + fo] = lt[fo * 129 + d];
    }
}

// ---------------------------------------------------------------------------
// Kernel A: QKV projection using pre-transposed W (d-major). Grid 768.
// Coalesced W reads (L1-resident), x via LDS broadcast, no in-loop barriers.
// Q -> [row][d] f16. V -> [row][d] f16.
// K -> Ktp[b][d2][s] dword layout (d-pair interleaved, k-major) via LDS
// repack, so score_kernel's per-d2 load is 256 B coalesced across lanes.
// ---------------------------------------------------------------------------
__global__ __launch_bounds__(256, 4) void qkv_kernel(
    const float* __restrict__ x, const float* __restrict__ Wt,
    const float* __restrict__ bq, const float* __restrict__ bk,
    const float* __restrict__ bv,
    h16* __restrict__ Qh, unsigned* __restrict__ Ktp, h16* __restrict__ V16)
{
    __shared__ float xs[8 * 128];          // 4 KB (reused for K repack)
    const int blk = blockIdx.x;
    const int p = blk >> 8;                // proj (block-uniform)
    const int row0 = (blk & 255) * 8;
    const int t = threadIdx.x;
    const int f = t & 127;
    const int h = t >> 7;                  // rows h*4 .. h*4+3

    ((float4*)xs)[t] = ((const float4*)(x + row0 * DD))[t];
    __syncthreads();

    const float* wt = Wt + p * 16384;
    float acc[4] = {0.f, 0.f, 0.f, 0.f};

    for (int d0 = 0; d0 < 128; d0 += 8) {
        float w[8];
        #pragma unroll
        for (int j = 0; j < 8; ++j) w[j] = wt[(d0 + j) * 128 + f];
        #pragma unroll
        for (int j = 0; j < 8; ++j) {
            #pragma unroll
            for (int r = 0; r < 4; ++r)
                acc[r] += w[j] * xs[(h * 4 + r) * 128 + d0 + j];  // broadcast
        }
    }

    const float bb_ = ((p == 0) ? bq : (p == 1) ? bk : bv)[f];

    if (p == 0) {
        #pragma unroll
        for (int r = 0; r < 4; ++r) {
            const int row = row0 + h * 4 + r;
            Qh[row * DD + f] = (h16)(1.f / (1.f + __expf(-(acc[r] + bb_))));
        }
    } else if (p == 2) {
        #pragma unroll
        for (int r = 0; r < 4; ++r) {
            const int row = row0 + h * 4 + r;
            V16[row * DD + f] = (h16)(acc[r] + bb_);
        }
    } else {
        // K: sigmoid -> LDS (padded stride 132) -> repack to Ktp[d2][s].
        __syncthreads();                   // xs reads all done
        h16* kst = (h16*)xs;               // reuse LDS, rows stride 132 h16
        #pragma unroll
        for (int r = 0; r < 4; ++r)
            kst[(h * 4 + r) * 132 + f] =
                (h16)(1.f / (1.f + __expf(-(acc[r] + bb_))));
        __syncthreads();
        const int b2 = row0 >> 10, s0 = row0 & 1023;
        unsigned* kb = Ktp + b2 * (64 * 1024);
        #pragma unroll
        for (int i = 0; i < 2; ++i) {
            const int idx = t + i * 256;
            const int d2 = idx >> 3, si = idx & 7;
            union { h16 hh[2]; unsigned u; } pk;
            pk.hh[0] = kst[si * 132 + 2 * d2];
            pk.hh[1] = kst[si * 132 + 2 * d2 + 1];
            kb[d2 * 1024 + s0 + si] = pk.u;
        }
    }
}

// ---------------------------------------------------------------------------
// Kernel S: raw Lukasiewicz scores -> f16. BARRIER-FREE, LDS-FREE.
// Grid 1024: job = (b | qg(4 rows) | k-half). Wave = one q row vs 512 k.
// q row held in 64 VGPRs (broadcast float4 loads). Inner loop over d2:
// load Ktp[d2][kb+lane] (dword = d-pair; 256 B coalesced, L1-resident),
// pk_sub/pk_max, fdot2 into two independent f32 chains.
// Causal: block-uniform skip of the k-half; wave-uniform nkg bound trims
// per-row work to ceil((qrow+1-kb0)/64) groups -> no masked-lane waste.
// Unwritten scg regions are always k > qrow and are masked on read by pv.
// ---------------------------------------------------------------------------
__global__ __launch_bounds__(256, 4) void score_kernel(
    const h16* __restrict__ Qh, const unsigned* __restrict__ Ktp,
    const int* __restrict__ causal_flag, h16* __restrict__ scg)
{
    const int job = blockIdx.x;
    const int kh = job & 1, qg = (job >> 1) & 255, b = job >> 9;
    const bool causal = (causal_flag[0] != 0);
    const int q0 = qg * 4;
    const int kb0 = kh * 512;
    if (causal && kh == 1 && q0 + 3 < 512) return;   // block-uniform skip

    const int t = threadIdx.x;
    const int wv = t >> 6, lane = t & 63;
    const int qrow = q0 + wv;

    int nkg = 8;                            // 8 groups x 64 k = 512 k
    if (causal) {
        nkg = ((qrow - kb0) >> 6) + 1;      // wave-uniform
        if (nkg > 8) nkg = 8;
    }

    float4 qf[16];                          // q row: 128 f16 in 64 VGPRs
    {
        const float4* qsrc = (const float4*)(Qh + (b * SS + qrow) * DD);
        #pragma unroll
        for (int i = 0; i < 16; ++i) qf[i] = qsrc[i];   // broadcast loads
    }

    const unsigned* kp = Ktp + b * (64 * 1024) + kb0 + lane;
    h16* srow = scg + (b * SS + qrow) * SS + kb0 + lane;
    const v2h zero = {(h16)0.0f, (h16)0.0f};

    for (int kg = 0; kg < nkg; ++kg) {
        const unsigned* kpg = kp + kg * 64;
        float a0 = 0.f, a1 = 0.f;           // two independent chains
        #pragma unroll
        for (int i = 0; i < 16; ++i) {
            union { float4 f; v2h hh[4]; } uq; uq.f = qf[i];
            #pragma unroll
            for (int e = 0; e < 4; ++e) {
                const int d2 = i * 4 + e;
                union { unsigned u; v2h hh; } kw;
                kw.u = kpg[d2 * 1024];      // 256 B coalesced across lanes
                const v2h diff =
                    __builtin_elementwise_max(uq.hh[e] - kw.hh, zero);
                if (e & 1) a1 = fdot2f(diff, a1);
                else       a0 = fdot2f(diff, a0);
            }
        }
        srow[kg * 64] = (h16)((1.f - (a0 + a1) * (1.f / DD)) * 10.f);
    }
}

// ---------------------------------------------------------------------------
// Kernel PV: masked-to-0 softmax + PV. Job = (b, qg, d-half), GRID 1024.
// Wave = q row for softmax (16 f16 scores/lane, shfl reduce; causal mask on
// read -> masked entries participate with score 0.0, per ref).
// PV: lane = (kcw 3b | d8 3b); kc = wv*8+kcw owns 32 k rows; k walk staggered
// by kcw*4 so the 8 concurrent LDS broadcasts hit 8 distinct banks.
// ---------------------------------------------------------------------------
__global__ __launch_bounds__(256, 4) void pv_kernel(
    const h16* __restrict__ scg, const h16* __restrict__ V16,
    const int* __restrict__ causal_flag, float* __restrict__ out)
{
    __shared__ float wl[4 * SS];           // 16 KB weights
    __shared__ float pvs[4][4][64];        // 4 KB partials

    const int job = blockIdx.x;
    const int dh = job & 1, qg = (job >> 1) & 255, b = job >> 9;
    const int q0 = qg * 4;
    const bool causal = (causal_flag[0] != 0);
    const int t = threadIdx.x;
    const int wv = t >> 6, lane = t & 63;
    const int qrow = q0 + wv;

    // ---- softmax over row qrow (16 scores/lane) ----
    const h16* srow = scg + (b * SS + qrow) * SS;   // 1024 h16 = 128 float4
    float sv[16];
    #pragma unroll
    for (int j = 0; j < 2; ++j) {
        const float4 raw = ((const float4*)srow)[j * 64 + lane];
        union { float4 f; v2h hh[4]; } us; us.f = raw;
        #pragma unroll
        for (int e = 0; e < 4; ++e) {
            const int kb_ = (j * 64 + lane) * 8 + 2 * e;
            float a0 = (float)us.hh[e].x, a1 = (float)us.hh[e].y;
            if (causal) {                  // mask k>qrow -> 0.0 (participates)
                if (kb_ + 0 > qrow) a0 = 0.f;
                if (kb_ + 1 > qrow) a1 = 0.f;
            }
            sv[j * 8 + 2 * e] = a0;
            sv[j * 8 + 2 * e + 1] = a1;
        }
    }
    float mx = -1e30f;
    #pragma unroll
    for (int i = 0; i < 16; ++i) mx = fmaxf(mx, sv[i]);
    #pragma unroll
    for (int o = 32; o > 0; o >>= 1) mx = fmaxf(mx, __shfl_xor(mx, o));
    float sum = 0.f;
    #pragma unroll
    for (int i = 0; i < 16; ++i) { sv[i] = __expf(sv[i] - mx); sum += sv[i]; }
    #pragma unroll
    for (int o = 32; o > 0; o >>= 1) sum += __shfl_xor(sum, o);
    const float inv = 1.f / sum;

    float4* wrow = (float4*)&wl[wv * SS];
    #pragma unroll
    for (int j = 0; j < 2; ++j) {
        #pragma unroll
        for (int hh = 0; hh < 2; ++hh) {
            float4 o4;
            o4.x = sv[j * 8 + hh * 4 + 0] * inv;
            o4.y = sv[j * 8 + hh * 4 + 1] * inv;
            o4.z = sv[j * 8 + hh * 4 + 2] * inv;
            o4.w = sv[j * 8 + hh * 4 + 3] * inv;
            wrow[(j * 64 + lane) * 2 + hh] = o4;
        }
    }
    __syncthreads();                       // weights visible

    // ---- PV ----
    const int d8 = t & 7, kcw = (t >> 3) & 7, kc = wv * 8 + kcw;
    float acc[4][8];
    #pragma unroll
    for (int qi = 0; qi < 4; ++qi)
        #pragma unroll
        for (int e = 0; e < 8; ++e) acc[qi][e] = 0.f;

    const h16* vbase = V16 + b * SS * DD + dh * 64 + d8 * 8;
    for (int ki = 0; ki < 32; ++ki) {
        const int ki2 = (ki + kcw * 4) & 31;          // bank stagger
        const int k = kc * 32 + ki2;
        const float4 vp = *(const float4*)(vbase + k * DD);
        union { float4 f; v2h hh[4]; } uv; uv.f = vp;
        float vf[8];
        #pragma unroll
        for (int e = 0; e < 4; ++e) {
            vf[2 * e]     = (float)uv.hh[e].x;
            vf[2 * e + 1] = (float)uv.hh[e].y;
        }
        #pragma unroll
        for (int qi = 0; qi < 4; ++qi) {
            const float wq = wl[qi * SS + k];         // 8-bank broadcast
            #pragma unroll
            for (int e = 0; e < 8; ++e) acc[qi][e] += wq * vf[e];
        }
    }
    // reduce over kcw (lane bits 3..5)
    #pragma unroll
    for (int o = 8; o < 64; o <<= 1)
        #pragma unroll
        for (int qi = 0; qi < 4; ++qi)
            #pragma unroll
            for (int e = 0; e < 8; ++e)
                acc[qi][e] += __shfl_xor(acc[qi][e], o);
    if (kcw == 0)
        #pragma unroll
        for (int qi = 0; qi < 4; ++qi)
            #pragma unroll
            for (int e = 0; e < 8; ++e)
                pvs[wv][qi][d8 * 8 + e] = acc[qi][e];
    __syncthreads();                       // partials visible

    {   // final reduce over the 4 waves' k ranges; coalesced store
        const int qi = t >> 6, d = t & 63;
        const float ssum = pvs[0][qi][d] + pvs[1][qi][d]
                         + pvs[2][qi][d] + pvs[3][qi][d];
        out[(b * SS + q0 + qi) * DD + dh * 64 + d] = ssum;
    }
}

extern "C" void kernel_launch(void* const* d_in, const int* in_sizes, int n_in,
                              void* d_out, int out_size, void* d_ws, size_t ws_size,
                              hipStream_t stream) {
    const float* x  = (const float*)d_in[0];
    const float* Wq = (const float*)d_in[1];
    const float* bq = (const float*)d_in[2];
    const float* Wk = (const float*)d_in[3];
    const float* bk = (const float*)d_in[4];
    const float* Wv = (const float*)d_in[5];
    const float* bv = (const float*)d_in[6];
    const int* causal = (const int*)d_in[7];
    float* out = (float*)d_out;

    const int rows = BB * SS;                     // 2048
    float*    Wt  = (float*)d_ws;                 // 192 KB
    h16*      Qh  = (h16*)(Wt + 3 * 16384);       // 512 KB
    unsigned* Ktp = (unsigned*)(Qh + rows * DD);  // 512 KB (2 x 64K dwords)
    h16*      V16 = (h16*)(Ktp + BB * 64 * 1024); // 512 KB
    h16*      scg = V16 + rows * DD;              // 4 MB f16 raw scores
    // total ws usage ~5.7 MB (<= proven 6.29 MB budget)

    wt_kernel<<<12, 256, 0, stream>>>(Wq, Wk, Wv, Wt);
    qkv_kernel<<<768, 256, 0, stream>>>(x, Wt, bq, bk, bv, Qh, Ktp, V16);
    score_kernel<<<1024, 256, 0, stream>>>(Qh, Ktp, causal, scg);
    pv_kernel<<<1024, 256, 0, stream>>>(scg, V16, causal, out);
}